// Round 3
// baseline (465.930 us; speedup 1.0000x reference)
//
#include <hip/hip_runtime.h>
#include <hip/hip_bf16.h>
#include <math.h>

typedef __bf16 bf16_t;
typedef __bf16 bf16x8 __attribute__((ext_vector_type(8)));
typedef __bf16 bf16x4 __attribute__((ext_vector_type(4)));
typedef float f32x4 __attribute__((ext_vector_type(4)));

// ---------- async global->LDS (16B per lane), wave-uniform base + lane*16 ----------
__device__ __forceinline__ void async_ld16(const void* g, void* l) {
  __builtin_amdgcn_global_load_lds(
      (const __attribute__((address_space(1))) unsigned int*)g,
      (__attribute__((address_space(3))) unsigned int*)l, 16, 0, 0);
}

// ---------- problem constants ----------
#define BATCH 2
#define SEQ   8192
#define EMB   768
#define NHEAD 12
#define HD    64
#define TOK   (BATCH*SEQ)          // 16384
#define GATH_PER_B 57344           // sum over heads of L_h = 4*(8192+4096+2048)

// group of head h: g = h>>2 ; L = 8192>>g ; s = 2048<<g ; r = 1<<g ; off = g
__device__ __forceinline__ int headoff(int h) {
  int g = h >> 2;
  int base = (g == 0) ? 0 : ((g == 1) ? 32768 : 49152);
  return base + (h & 3) * (8192 >> g);
}

// ---------- fp32 -> bf16 cast (weights only) ----------
__global__ void k_cast(const float* __restrict__ in, bf16_t* __restrict__ out, int n) {
  int i = (blockIdx.x * blockDim.x + threadIdx.x) * 4;
  if (i < n) {
    float4 v = *(const float4*)(in + i);
    bf16_t o[4] = {(bf16_t)v.x, (bf16_t)v.y, (bf16_t)v.z, (bf16_t)v.w};
    *(uint2*)(out + i) = *(uint2*)o;
  }
}

// ---------- QKV GEMM, fused input cast + dilated gather epilogue ----------
// A: [16384,768] fp32 (cast inline during staging); W slice: [768,768] bf16.
// z=0 (Q, scaled 1/8) and z=1 (K): scatter-store into gathered layout [hb+jj][64].
// z=2 (V): plain [tok][768] store (transposed later by k_gather_v).
__global__ __launch_bounds__(256, 2)
void k_gemm_qkv(const float* __restrict__ qf, const float* __restrict__ kf,
                const float* __restrict__ vf, const bf16_t* __restrict__ wqkv,
                const float* __restrict__ qkv_bias,
                bf16_t* __restrict__ Qg, bf16_t* __restrict__ Kg, bf16_t* __restrict__ Vb) {
  const int N = 768, K = 768;
  int z = blockIdx.z;
  const float* A = (z == 0) ? qf : (z == 1) ? kf : vf;
  const bf16_t* W = wqkv + (size_t)z * N * K;
  const float* bias = qkv_bias + z * N;

  __shared__ bf16_t As[128][32];
  __shared__ bf16_t Bs[128][32];

  int tid = threadIdx.x;
  int wave = tid >> 6, lane = tid & 63;
  int q = lane >> 4, c = lane & 15;
  int wm = (wave & 1) * 64, wn = (wave >> 1) * 64;
  int m0 = blockIdx.y * 128, n0 = blockIdx.x * 128;

  f32x4 acc[4][4];
#pragma unroll
  for (int i = 0; i < 4; i++)
#pragma unroll
    for (int j = 0; j < 4; j++) acc[i][j] = (f32x4){0.f, 0.f, 0.f, 0.f};

  for (int k0 = 0; k0 < K; k0 += 32) {
#pragma unroll
    for (int it = 0; it < 2; ++it) {
      int ch = tid + it * 256;          // 512 chunks of 16B(bf16) / 32B(fp32)
      int row = ch >> 2, kb8 = (ch & 3) << 3;
      // A: fp32 load + cvt + ds_write
      const float* src = A + (size_t)(m0 + row) * K + k0 + kb8;
      float4 u0 = *(const float4*)src;
      float4 u1 = *(const float4*)(src + 4);
      __attribute__((aligned(16))) bf16_t t8[8] = {
          (bf16_t)u0.x, (bf16_t)u0.y, (bf16_t)u0.z, (bf16_t)u0.w,
          (bf16_t)u1.x, (bf16_t)u1.y, (bf16_t)u1.z, (bf16_t)u1.w};
      *(uint4*)&As[row][kb8] = *(uint4*)t8;
      // B: async DMA (already bf16)
      async_ld16(W + (size_t)(n0 + row) * K + k0 + kb8, &Bs[row][kb8]);
    }
    __syncthreads();
    bf16x8 af[4], bfr[4];
#pragma unroll
    for (int mi = 0; mi < 4; mi++) af[mi] = *(const bf16x8*)&As[wm + mi * 16 + c][q * 8];
#pragma unroll
    for (int nj = 0; nj < 4; nj++) bfr[nj] = *(const bf16x8*)&Bs[wn + nj * 16 + c][q * 8];
#pragma unroll
    for (int mi = 0; mi < 4; mi++)
#pragma unroll
      for (int nj = 0; nj < 4; nj++)
        acc[mi][nj] = __builtin_amdgcn_mfma_f32_16x16x32_bf16(af[mi], bfr[nj], acc[mi][nj], 0, 0, 0);
    __syncthreads();
  }

  if (z == 2) {
#pragma unroll
    for (int mi = 0; mi < 4; mi++)
#pragma unroll
      for (int nj = 0; nj < 4; nj++)
#pragma unroll
        for (int rg = 0; rg < 4; rg++) {
          int row = m0 + wm + mi * 16 + q * 4 + rg;
          int col = n0 + wn + nj * 16 + c;
          Vb[(size_t)row * N + col] = (bf16_t)(acc[mi][nj][rg] + bias[col]);
        }
  } else {
    bf16_t* dst = (z == 0) ? Qg : Kg;
    float qscale = (z == 0) ? 0.125f : 1.0f;
#pragma unroll
    for (int mi = 0; mi < 4; mi++)
#pragma unroll
      for (int nj = 0; nj < 4; nj++) {
        int e = n0 + wn + nj * 16 + c;
        int h = e >> 6, dim = e & 63, g2 = h >> 2;
        int rm1 = (1 << g2) - 1, sh = 11 + g2;
        int smask = (2048 << g2) - 1;
        int ho = headoff(h);
#pragma unroll
        for (int rg = 0; rg < 4; rg++) {
          int row = m0 + wm + mi * 16 + q * 4 + rg;
          float v = (acc[mi][nj][rg] + bias[e]) * qscale;
          int bb = row >> 13, p = row & 8191;
          int t = (p & smask) - g2;           // off == g2
          if (t >= 0 && (t & rm1) == 0) {
            int jj = (p >> sh) * 2048 + (t >> g2);
            dst[(size_t)(bb * GATH_PER_B + ho + jj) * HD + dim] = (bf16_t)v;
          }
        }
      }
  }
}

// ---------- output GEMM: fp32 out ----------
__global__ __launch_bounds__(256, 2)
void k_gemm_out(const bf16_t* __restrict__ A, const bf16_t* __restrict__ W,
                const float* __restrict__ bias, float* __restrict__ C) {
  const int N = 768, K = 768;
  __shared__ bf16_t As[128][32];
  __shared__ bf16_t Bs[128][32];

  int tid = threadIdx.x;
  int wave = tid >> 6, lane = tid & 63;
  int q = lane >> 4, c = lane & 15;
  int wm = (wave & 1) * 64, wn = (wave >> 1) * 64;
  int m0 = blockIdx.y * 128, n0 = blockIdx.x * 128;

  f32x4 acc[4][4];
#pragma unroll
  for (int i = 0; i < 4; i++)
#pragma unroll
    for (int j = 0; j < 4; j++) acc[i][j] = (f32x4){0.f, 0.f, 0.f, 0.f};

  for (int k0 = 0; k0 < K; k0 += 32) {
#pragma unroll
    for (int it = 0; it < 2; ++it) {
      int ch = tid + it * 256;
      int row = ch >> 2, kb8 = (ch & 3) << 3;
      async_ld16(A + (size_t)(m0 + row) * K + k0 + kb8, &As[row][kb8]);
      async_ld16(W + (size_t)(n0 + row) * K + k0 + kb8, &Bs[row][kb8]);
    }
    __syncthreads();
    bf16x8 af[4], bfr[4];
#pragma unroll
    for (int mi = 0; mi < 4; mi++) af[mi] = *(const bf16x8*)&As[wm + mi * 16 + c][q * 8];
#pragma unroll
    for (int nj = 0; nj < 4; nj++) bfr[nj] = *(const bf16x8*)&Bs[wn + nj * 16 + c][q * 8];
#pragma unroll
    for (int mi = 0; mi < 4; mi++)
#pragma unroll
      for (int nj = 0; nj < 4; nj++)
        acc[mi][nj] = __builtin_amdgcn_mfma_f32_16x16x32_bf16(af[mi], bfr[nj], acc[mi][nj], 0, 0, 0);
    __syncthreads();
  }
#pragma unroll
  for (int mi = 0; mi < 4; mi++)
#pragma unroll
    for (int nj = 0; nj < 4; nj++)
#pragma unroll
      for (int rg = 0; rg < 4; rg++) {
        int row = m0 + wm + mi * 16 + q * 4 + rg;
        int col = n0 + wn + nj * 16 + c;
        C[(size_t)row * N + col] = acc[mi][nj][rg] + bias[col];
      }
}

// ---------- V gather: Vb [tok][768] -> Vt [head][dim][L], slot-permuted ----------
// Within each 64-pos block of Vt, slot t holds dilated pos (t&3)*16 + (t>>2)
// (matches attn's P half-tile packing: storage col c*4+nj <-> pos nj*16+c).
__global__ __launch_bounds__(256)
void k_gather_v(const bf16_t* __restrict__ Vb, bf16_t* __restrict__ Vt) {
  int h = blockIdx.y, b = blockIdx.z;
  int g = h >> 2;
  int L = 8192 >> g;
  int jj0 = blockIdx.x * 64;
  if (jj0 >= L) return;
  int s = 2048 << g;
  int hb = b * GATH_PER_B + headoff(h);
  int tid = threadIdx.x;

  __shared__ bf16_t tile[64][72];

#pragma unroll
  for (int it = 0; it < 2; ++it) {
    int ch = tid + it * 256;            // 512 chunks: 64 rows x 8 chunks of 16B
    int rowl = ch >> 3, db = (ch & 7) << 3;
    int jj = jj0 + rowl;
    int p = (jj >> 11) * s + g + ((jj & 2047) << g);
    *(uint4*)&tile[rowl][db] = *(const uint4*)(Vb + ((size_t)(b * SEQ + p)) * EMB + h * HD + db);
  }
  __syncthreads();
  int dim = tid >> 2, sub = tid & 3;
  __attribute__((aligned(16))) bf16_t tmp[16];
#pragma unroll
  for (int sl = 0; sl < 16; sl++) {
    int t = sub * 16 + sl;
    int pos = (t & 3) * 16 + (t >> 2);
    tmp[sl] = tile[pos][dim];
  }
  size_t vdst = ((size_t)hb) * HD + (size_t)dim * L + jj0 + sub * 16;
  *(uint4*)(Vt + vdst) = *(uint4*)&tmp[0];
  *(uint4*)(Vt + vdst + 8) = *(uint4*)&tmp[8];
}

// ---------- flash attention (no-max softmax, swizzled LDS, 48KB -> 3 blocks/CU) ----------
__global__ __launch_bounds__(256, 3)
void k_attn(const bf16_t* __restrict__ Qg, const bf16_t* __restrict__ Kg,
            const bf16_t* __restrict__ Vt, bf16_t* __restrict__ xattn) {
  // block id = qt*56 + seg: all 16 Q-tiles of a segment share an XCD (56 % 8 == 0)
  int u = blockIdx.x;
  int seg = u % 56, qt = u / 56;
  int b = seg / 28, t = seg % 28;
  int g, h, si;
  if (t < 16)      { g = 0; h = t >> 2;              si = t & 3; }
  else if (t < 24) { g = 1; h = 4 + ((t - 16) >> 1); si = (t - 16) & 1; }
  else             { g = 2; h = 8 + (t - 24);        si = 0; }
  int L = 8192 >> g, s = 2048 << g;
  int hb = b * GATH_PER_B + headoff(h);
  int jj0 = si * 2048 + qt * 128;
  int kvbase = si * 2048;

  __shared__ bf16_t Ps[128][64];      // 16KB: P half-tile round-trip; doubles as Q staging
  __shared__ bf16_t Ks[128][64];      // 16KB
  __shared__ bf16_t Vs[64][128];      // 16KB ([dim][slot], slots pre-permuted per 64-block)

  int tid = threadIdx.x, wave = tid >> 6, lane = tid & 63;
  int q = lane >> 4, c = lane & 15;
  int cx = c & 7;
  int wm = wave * 32;

  // stage Q tile [128][64] into Ps area, chunk-swizzled (pc holds logical pc^(row&7))
  bf16_t* Qs = &Ps[0][0];
#pragma unroll
  for (int it = 0; it < 4; ++it) {
    int ch = tid + it * 256;
    int row = ch >> 3, pc = ch & 7, lc = pc ^ (row & 7);
    async_ld16(Qg + ((size_t)(hb + jj0 + row)) * HD + lc * 8, Qs + ch * 8);
  }
  __syncthreads();
  bf16x8 aq[2][2];
#pragma unroll
  for (int mi = 0; mi < 2; mi++)
#pragma unroll
    for (int kq = 0; kq < 2; kq++) {
      int pch = (kq * 4 + q) ^ cx;
      aq[mi][kq] = *(const bf16x8*)(Qs + (size_t)(wm + mi * 16 + c) * HD + pch * 8);
    }

  float lrow[2][4];
  f32x4 O[2][4];
#pragma unroll
  for (int mi = 0; mi < 2; mi++)
#pragma unroll
    for (int rg = 0; rg < 4; rg++) lrow[mi][rg] = 0.f;
#pragma unroll
  for (int mi = 0; mi < 2; mi++)
#pragma unroll
    for (int vd = 0; vd < 4; vd++) O[mi][vd] = (f32x4){0.f, 0.f, 0.f, 0.f};

  for (int kt = 0; kt < 16; ++kt) {
    __syncthreads();                  // prior-iter Ks/Vs reads complete
#pragma unroll
    for (int it = 0; it < 4; ++it) {
      int ch = tid + it * 256;
      int row = ch >> 3, pc = ch & 7, lc = pc ^ (row & 7);
      async_ld16(Kg + ((size_t)(hb + kvbase + kt * 128 + row)) * HD + lc * 8,
                 &Ks[0][0] + ch * 8);
    }
#pragma unroll
    for (int it = 0; it < 4; ++it) {
      int ch = tid + it * 256;
      int dim = ch >> 4, pc = ch & 15, lc = pc ^ (dim & 7);
      async_ld16(Vt + ((size_t)hb) * HD + (size_t)dim * L + kvbase + kt * 128 + lc * 8,
                 &Vs[0][0] + ch * 8);
    }
    __syncthreads();                  // staging visible

    // S = Q K^T  (Q pre-scaled by 1/8)
    f32x4 Sv[2][8];
#pragma unroll
    for (int mi = 0; mi < 2; mi++)
#pragma unroll
      for (int nj = 0; nj < 8; nj++) Sv[mi][nj] = (f32x4){0.f, 0.f, 0.f, 0.f};
#pragma unroll
    for (int kq = 0; kq < 2; kq++) {
      int pch = (kq * 4 + q) ^ cx;
      bf16x8 bk[8];
#pragma unroll
      for (int nj = 0; nj < 8; nj++) bk[nj] = *(const bf16x8*)&Ks[nj * 16 + c][pch * 8];
#pragma unroll
      for (int mi = 0; mi < 2; mi++)
#pragma unroll
        for (int nj = 0; nj < 8; nj++)
          Sv[mi][nj] = __builtin_amdgcn_mfma_f32_16x16x32_bf16(aq[mi][kq], bk[nj], Sv[mi][nj], 0, 0, 0);
    }

    // two KV halves of 64: exp+pack 4 vals -> ds_write_b64 into Ps[128][64]; then PV
#pragma unroll
    for (int half = 0; half < 2; ++half) {
#pragma unroll
      for (int mi = 0; mi < 2; mi++)
#pragma unroll
        for (int rg = 0; rg < 4; rg++) {
          bf16x4 p4;
          float rs = 0.f;
#pragma unroll
          for (int j = 0; j < 4; j++) {
            float p = __expf(Sv[mi][half * 4 + j][rg]);
            rs += p;
            p4[j] = (bf16_t)p;
          }
          lrow[mi][rg] += rs;
          int row = wm + mi * 16 + q * 4 + rg;
          int u8 = c ^ ((row & 7) << 1);          // 8B-unit swizzle
          *(bf16x4*)((char*)&Ps[row][0] + u8 * 8) = p4;
        }
      // no barrier: Ps rows wm..wm+31 wave-private (DS ops in-order within a wave)
#pragma unroll
      for (int kk2 = 0; kk2 < 2; ++kk2) {
        bf16x8 ap[2], bv[4];
#pragma unroll
        for (int mi = 0; mi < 2; mi++) {
          int u8 = (kk2 * 8 + q * 2) ^ (cx << 1); // even: b128-aligned
          ap[mi] = *(const bf16x8*)((char*)&Ps[wm + mi * 16 + c][0] + u8 * 8);
        }
#pragma unroll
        for (int vd = 0; vd < 4; vd++) {
          int pch = (half * 8 + kk2 * 4 + q) ^ cx;
          bv[vd] = *(const bf16x8*)&Vs[vd * 16 + c][pch * 8];
        }
#pragma unroll
        for (int mi = 0; mi < 2; mi++)
#pragma unroll
          for (int vd = 0; vd < 4; vd++)
            O[mi][vd] = __builtin_amdgcn_mfma_f32_16x16x32_bf16(ap[mi], bv[vd], O[mi][vd], 0, 0, 0);
      }
    }
  }

  // epilogue: l = cross-lane rowsum; out = O / l / 3, scattered to original positions
  const float inv3 = 1.0f / 3.0f;
#pragma unroll
  for (int mi = 0; mi < 2; mi++)
#pragma unroll
    for (int rg = 0; rg < 4; rg++) {
      float l = lrow[mi][rg];
#pragma unroll
      for (int d = 1; d < 16; d <<= 1) l += __shfl_xor(l, d, 64);
      float invl = inv3 / l;
      int jj = jj0 + wm + mi * 16 + q * 4 + rg;
      int p = si * s + g + ((jj & 2047) << g);
      size_t base = ((size_t)(b * SEQ + p)) * EMB + h * HD;
#pragma unroll
      for (int vd = 0; vd < 4; vd++)
        xattn[base + vd * 16 + c] = (bf16_t)(O[mi][vd][rg] * invl);
    }
}

// ---------- LayerNorm (wave per row) ----------
__global__ __launch_bounds__(256)
void k_ln(const bf16_t* __restrict__ x, const float* __restrict__ lnw,
          const float* __restrict__ lnb, bf16_t* __restrict__ y) {
  int wave = threadIdx.x >> 6, lane = threadIdx.x & 63;
  int row = blockIdx.x * 4 + wave;
  const bf16_t* xr = x + (size_t)row * EMB;
  float v[12], s = 0.f, s2 = 0.f;
#pragma unroll
  for (int j = 0; j < 12; j++) {
    v[j] = (float)xr[lane + j * 64];
    s += v[j];
    s2 += v[j] * v[j];
  }
#pragma unroll
  for (int d = 1; d < 64; d <<= 1) { s += __shfl_xor(s, d, 64); s2 += __shfl_xor(s2, d, 64); }
  float mu = s * (1.f / 768.f);
  float var = s2 * (1.f / 768.f) - mu * mu;
  float rstd = rsqrtf(var + 1e-5f);
  bf16_t* yr = y + (size_t)row * EMB;
#pragma unroll
  for (int j = 0; j < 12; j++) {
    int e = lane + j * 64;
    yr[e] = (bf16_t)((v[j] - mu) * rstd * lnw[e] + lnb[e]);
  }
}

extern "C" void kernel_launch(void* const* d_in, const int* in_sizes, int n_in,
                              void* d_out, int out_size, void* d_ws, size_t ws_size,
                              hipStream_t stream) {
  const float* query = (const float*)d_in[0];
  const float* key   = (const float*)d_in[1];
  const float* value = (const float*)d_in[2];
  const float* qkv_w = (const float*)d_in[3];
  const float* qkv_b = (const float*)d_in[4];
  const float* ln_w  = (const float*)d_in[5];
  const float* ln_b  = (const float*)d_in[6];
  const float* out_w = (const float*)d_in[7];
  const float* out_b = (const float*)d_in[8];
  float* out = (float*)d_out;

  char* ws = (char*)d_ws;
  const size_t A = (size_t)TOK * EMB * 2;   // 25,165,824 bytes per full-tensor slot
  bf16_t* Qg    = (bf16_t*)(ws + 0 * A);    // gathered Q (pre-scaled 1/8), 14.68MB
  bf16_t* Kg    = (bf16_t*)(ws + 1 * A);    // gathered K
  bf16_t* Vb    = (bf16_t*)(ws + 2 * A);    // V, plain [tok][768]
  bf16_t* Vt    = (bf16_t*)(ws + 3 * A);    // V transposed+permuted gathered
  bf16_t* xattn = (bf16_t*)(ws + 4 * A);
  bf16_t* xnorm = (bf16_t*)(ws + 5 * A);
  bf16_t* wqkv  = (bf16_t*)(ws + 6 * A);
  bf16_t* wout  = (bf16_t*)(ws + 6 * A + (size_t)2304 * 768 * 2);

  // 1. weight casts fp32 -> bf16 (inputs are cast inline in k_gemm_qkv)
  k_cast<<<1728, 256, 0, stream>>>(qkv_w, wqkv, 2304 * 768);
  k_cast<<<576, 256, 0, stream>>>(out_w, wout, 768 * 768);

  // 2. QKV projection, fused cast + Q/K dilated-gather epilogue
  dim3 gq(6, 128, 3);
  k_gemm_qkv<<<gq, 256, 0, stream>>>(query, key, value, wqkv, qkv_b, Qg, Kg, Vb);

  // 3. V gather (transpose + slot-permute)
  dim3 gg(128, 12, 2);
  k_gather_v<<<gg, 256, 0, stream>>>(Vb, Vt);

  // 4. attention (zero xattn first: non-selected positions must be 0)
  hipMemsetAsync(xattn, 0, A, stream);
  k_attn<<<896, 256, 0, stream>>>(Qg, Kg, Vt, xattn);

  // 5. MAGNETO LN
  k_ln<<<4096, 256, 0, stream>>>(xattn, ln_w, ln_b, xnorm);

  // 6. output projection
  dim3 go(6, 128);
  k_gemm_out<<<go, 256, 0, stream>>>(xnorm, wout, out_b, out);
}

// Round 4
// 453.142 us; speedup vs baseline: 1.0282x; 1.0282x over previous
//
#include <hip/hip_runtime.h>
#include <hip/hip_bf16.h>
#include <math.h>

typedef __bf16 bf16_t;
typedef __bf16 bf16x8 __attribute__((ext_vector_type(8)));
typedef __bf16 bf16x4 __attribute__((ext_vector_type(4)));
typedef float f32x4 __attribute__((ext_vector_type(4)));

// ---------- async global->LDS (16B per lane), wave-uniform base + lane*16 ----------
__device__ __forceinline__ void async_ld16(const void* g, void* l) {
  __builtin_amdgcn_global_load_lds(
      (const __attribute__((address_space(1))) unsigned int*)g,
      (__attribute__((address_space(3))) unsigned int*)l, 16, 0, 0);
}

// ---------- problem constants ----------
#define BATCH 2
#define SEQ   8192
#define EMB   768
#define NHEAD 12
#define HD    64
#define TOK   (BATCH*SEQ)          // 16384
#define GATH_PER_B 57344           // sum over heads of L_h = 4*(8192+4096+2048)

// group of head h: g = h>>2 ; L = 8192>>g ; s = 2048<<g ; r = 1<<g ; off = g
__device__ __forceinline__ int headoff(int h) {
  int g = h >> 2;
  int base = (g == 0) ? 0 : ((g == 1) ? 32768 : 49152);
  return base + (h & 3) * (8192 >> g);
}

// ---------- fp32 -> bf16 cast (8 elems/thread, 16B stores) ----------
__global__ void k_cast(const float* __restrict__ in, bf16_t* __restrict__ out, int n) {
  int i = (blockIdx.x * blockDim.x + threadIdx.x) * 8;
  if (i < n) {
    float4 a = *(const float4*)(in + i);
    float4 b = *(const float4*)(in + i + 4);
    __attribute__((aligned(16))) bf16_t o[8] = {
        (bf16_t)a.x, (bf16_t)a.y, (bf16_t)a.z, (bf16_t)a.w,
        (bf16_t)b.x, (bf16_t)b.y, (bf16_t)b.z, (bf16_t)b.w};
    *(uint4*)(out + i) = *(uint4*)o;
  }
}

// ---------- QKV GEMM (bf16 A via async DMA) + fused dilated-gather epilogue ----------
// z=0 (Q, scaled 1/8) and z=1 (K): scatter-store into gathered layout [hb+jj][64].
// z=2 (V): plain [tok][768] store (transposed later by k_gather_v).
__global__ __launch_bounds__(256, 2)
void k_gemm_qkv(const bf16_t* __restrict__ qb, const bf16_t* __restrict__ kb,
                const bf16_t* __restrict__ vb, const bf16_t* __restrict__ wqkv,
                const float* __restrict__ qkv_bias,
                bf16_t* __restrict__ Qg, bf16_t* __restrict__ Kg, bf16_t* __restrict__ Vb) {
  const int N = 768, K = 768;
  int z = blockIdx.z;
  const bf16_t* A = (z == 0) ? qb : (z == 1) ? kb : vb;
  const bf16_t* W = wqkv + (size_t)z * N * K;
  const float* bias = qkv_bias + z * N;

  __shared__ bf16_t As[128][32];
  __shared__ bf16_t Bs[128][32];

  int tid = threadIdx.x;
  int wave = tid >> 6, lane = tid & 63;
  int q = lane >> 4, c = lane & 15;
  int wm = (wave & 1) * 64, wn = (wave >> 1) * 64;
  int m0 = blockIdx.y * 128, n0 = blockIdx.x * 128;

  f32x4 acc[4][4];
#pragma unroll
  for (int i = 0; i < 4; i++)
#pragma unroll
    for (int j = 0; j < 4; j++) acc[i][j] = (f32x4){0.f, 0.f, 0.f, 0.f};

  for (int k0 = 0; k0 < K; k0 += 32) {
#pragma unroll
    for (int it = 0; it < 2; ++it) {
      int ch = tid + it * 256;          // 512 chunks of 16B
      int row = ch >> 2, kb8 = (ch & 3) << 3;
      async_ld16(A + (size_t)(m0 + row) * K + k0 + kb8, &As[row][kb8]);
      async_ld16(W + (size_t)(n0 + row) * K + k0 + kb8, &Bs[row][kb8]);
    }
    __syncthreads();
    bf16x8 af[4], bfr[4];
#pragma unroll
    for (int mi = 0; mi < 4; mi++) af[mi] = *(const bf16x8*)&As[wm + mi * 16 + c][q * 8];
#pragma unroll
    for (int nj = 0; nj < 4; nj++) bfr[nj] = *(const bf16x8*)&Bs[wn + nj * 16 + c][q * 8];
#pragma unroll
    for (int mi = 0; mi < 4; mi++)
#pragma unroll
      for (int nj = 0; nj < 4; nj++)
        acc[mi][nj] = __builtin_amdgcn_mfma_f32_16x16x32_bf16(af[mi], bfr[nj], acc[mi][nj], 0, 0, 0);
    __syncthreads();
  }

  if (z == 2) {
#pragma unroll
    for (int mi = 0; mi < 4; mi++)
#pragma unroll
      for (int nj = 0; nj < 4; nj++)
#pragma unroll
        for (int rg = 0; rg < 4; rg++) {
          int row = m0 + wm + mi * 16 + q * 4 + rg;
          int col = n0 + wn + nj * 16 + c;
          Vb[(size_t)row * N + col] = (bf16_t)(acc[mi][nj][rg] + bias[col]);
        }
  } else {
    bf16_t* dst = (z == 0) ? Qg : Kg;
    float qscale = (z == 0) ? 0.125f : 1.0f;
#pragma unroll
    for (int mi = 0; mi < 4; mi++)
#pragma unroll
      for (int nj = 0; nj < 4; nj++) {
        int e = n0 + wn + nj * 16 + c;
        int h = e >> 6, dim = e & 63, g2 = h >> 2;
        int rm1 = (1 << g2) - 1, sh = 11 + g2;
        int smask = (2048 << g2) - 1;
        int ho = headoff(h);
#pragma unroll
        for (int rg = 0; rg < 4; rg++) {
          int row = m0 + wm + mi * 16 + q * 4 + rg;
          float v = (acc[mi][nj][rg] + bias[e]) * qscale;
          int bb = row >> 13, p = row & 8191;
          int t = (p & smask) - g2;           // off == g2
          if (t >= 0 && (t & rm1) == 0) {
            int jj = (p >> sh) * 2048 + (t >> g2);
            dst[(size_t)(bb * GATH_PER_B + ho + jj) * HD + dim] = (bf16_t)v;
          }
        }
      }
  }
}

// ---------- output GEMM: fp32 out ----------
__global__ __launch_bounds__(256, 2)
void k_gemm_out(const bf16_t* __restrict__ A, const bf16_t* __restrict__ W,
                const float* __restrict__ bias, float* __restrict__ C) {
  const int N = 768, K = 768;
  __shared__ bf16_t As[128][32];
  __shared__ bf16_t Bs[128][32];

  int tid = threadIdx.x;
  int wave = tid >> 6, lane = tid & 63;
  int q = lane >> 4, c = lane & 15;
  int wm = (wave & 1) * 64, wn = (wave >> 1) * 64;
  int m0 = blockIdx.y * 128, n0 = blockIdx.x * 128;

  f32x4 acc[4][4];
#pragma unroll
  for (int i = 0; i < 4; i++)
#pragma unroll
    for (int j = 0; j < 4; j++) acc[i][j] = (f32x4){0.f, 0.f, 0.f, 0.f};

  for (int k0 = 0; k0 < K; k0 += 32) {
#pragma unroll
    for (int it = 0; it < 2; ++it) {
      int ch = tid + it * 256;
      int row = ch >> 2, kb8 = (ch & 3) << 3;
      async_ld16(A + (size_t)(m0 + row) * K + k0 + kb8, &As[row][kb8]);
      async_ld16(W + (size_t)(n0 + row) * K + k0 + kb8, &Bs[row][kb8]);
    }
    __syncthreads();
    bf16x8 af[4], bfr[4];
#pragma unroll
    for (int mi = 0; mi < 4; mi++) af[mi] = *(const bf16x8*)&As[wm + mi * 16 + c][q * 8];
#pragma unroll
    for (int nj = 0; nj < 4; nj++) bfr[nj] = *(const bf16x8*)&Bs[wn + nj * 16 + c][q * 8];
#pragma unroll
    for (int mi = 0; mi < 4; mi++)
#pragma unroll
      for (int nj = 0; nj < 4; nj++)
        acc[mi][nj] = __builtin_amdgcn_mfma_f32_16x16x32_bf16(af[mi], bfr[nj], acc[mi][nj], 0, 0, 0);
    __syncthreads();
  }
#pragma unroll
  for (int mi = 0; mi < 4; mi++)
#pragma unroll
    for (int nj = 0; nj < 4; nj++)
#pragma unroll
      for (int rg = 0; rg < 4; rg++) {
        int row = m0 + wm + mi * 16 + q * 4 + rg;
        int col = n0 + wn + nj * 16 + c;
        C[(size_t)row * N + col] = acc[mi][nj][rg] + bias[col];
      }
}

// ---------- V gather: Vb [tok][768] -> Vt [head][dim][L], slot-permuted ----------
// Within each 64-pos block of Vt, slot t holds dilated pos (t&3)*16 + (t>>2)
// (matches attn's P half-tile packing: storage col c*4+nj <-> pos nj*16+c).
__global__ __launch_bounds__(256)
void k_gather_v(const bf16_t* __restrict__ Vb, bf16_t* __restrict__ Vt) {
  int h = blockIdx.y, b = blockIdx.z;
  int g = h >> 2;
  int L = 8192 >> g;
  int jj0 = blockIdx.x * 64;
  if (jj0 >= L) return;
  int s = 2048 << g;
  int hb = b * GATH_PER_B + headoff(h);
  int tid = threadIdx.x;

  __shared__ bf16_t tile[64][72];

#pragma unroll
  for (int it = 0; it < 2; ++it) {
    int ch = tid + it * 256;            // 512 chunks: 64 rows x 8 chunks of 16B
    int rowl = ch >> 3, db = (ch & 7) << 3;
    int jj = jj0 + rowl;
    int p = (jj >> 11) * s + g + ((jj & 2047) << g);
    *(uint4*)&tile[rowl][db] = *(const uint4*)(Vb + ((size_t)(b * SEQ + p)) * EMB + h * HD + db);
  }
  __syncthreads();
  int dim = tid >> 2, sub = tid & 3;
  __attribute__((aligned(16))) bf16_t tmp[16];
#pragma unroll
  for (int sl = 0; sl < 16; sl++) {
    int t = sub * 16 + sl;
    int pos = (t & 3) * 16 + (t >> 2);
    tmp[sl] = tile[pos][dim];
  }
  size_t vdst = ((size_t)hb) * HD + (size_t)dim * L + jj0 + sub * 16;
  *(uint4*)(Vt + vdst) = *(uint4*)&tmp[0];
  *(uint4*)(Vt + vdst + 8) = *(uint4*)&tmp[8];
}

// ---------- flash attention (no-max softmax, swizzled LDS, 48KB -> 3 blocks/CU) ----------
__global__ __launch_bounds__(256, 3)
void k_attn(const bf16_t* __restrict__ Qg, const bf16_t* __restrict__ Kg,
            const bf16_t* __restrict__ Vt, bf16_t* __restrict__ xattn) {
  // block id = qt*56 + seg: all 16 Q-tiles of a segment share an XCD (56 % 8 == 0)
  int u = blockIdx.x;
  int seg = u % 56, qt = u / 56;
  int b = seg / 28, t = seg % 28;
  int g, h, si;
  if (t < 16)      { g = 0; h = t >> 2;              si = t & 3; }
  else if (t < 24) { g = 1; h = 4 + ((t - 16) >> 1); si = (t - 16) & 1; }
  else             { g = 2; h = 8 + (t - 24);        si = 0; }
  int L = 8192 >> g, s = 2048 << g;
  int hb = b * GATH_PER_B + headoff(h);
  int jj0 = si * 2048 + qt * 128;
  int kvbase = si * 2048;

  __shared__ bf16_t Ps[128][64];      // 16KB: P half-tile round-trip; doubles as Q staging
  __shared__ bf16_t Ks[128][64];      // 16KB
  __shared__ bf16_t Vs[64][128];      // 16KB ([dim][slot], slots pre-permuted per 64-block)

  int tid = threadIdx.x, wave = tid >> 6, lane = tid & 63;
  int q = lane >> 4, c = lane & 15;
  int cx = c & 7;
  int wm = wave * 32;

  // stage Q tile [128][64] into Ps area, chunk-swizzled (pc holds logical pc^(row&7))
  bf16_t* Qs = &Ps[0][0];
#pragma unroll
  for (int it = 0; it < 4; ++it) {
    int ch = tid + it * 256;
    int row = ch >> 3, pc = ch & 7, lc = pc ^ (row & 7);
    async_ld16(Qg + ((size_t)(hb + jj0 + row)) * HD + lc * 8, Qs + ch * 8);
  }
  __syncthreads();
  bf16x8 aq[2][2];
#pragma unroll
  for (int mi = 0; mi < 2; mi++)
#pragma unroll
    for (int kq = 0; kq < 2; kq++) {
      int pch = (kq * 4 + q) ^ cx;
      aq[mi][kq] = *(const bf16x8*)(Qs + (size_t)(wm + mi * 16 + c) * HD + pch * 8);
    }

  float lrow[2][4];
  f32x4 O[2][4];
#pragma unroll
  for (int mi = 0; mi < 2; mi++)
#pragma unroll
    for (int rg = 0; rg < 4; rg++) lrow[mi][rg] = 0.f;
#pragma unroll
  for (int mi = 0; mi < 2; mi++)
#pragma unroll
    for (int vd = 0; vd < 4; vd++) O[mi][vd] = (f32x4){0.f, 0.f, 0.f, 0.f};

  for (int kt = 0; kt < 16; ++kt) {
    __syncthreads();                  // prior-iter Ks/Vs reads complete
#pragma unroll
    for (int it = 0; it < 4; ++it) {
      int ch = tid + it * 256;
      int row = ch >> 3, pc = ch & 7, lc = pc ^ (row & 7);
      async_ld16(Kg + ((size_t)(hb + kvbase + kt * 128 + row)) * HD + lc * 8,
                 &Ks[0][0] + ch * 8);
    }
#pragma unroll
    for (int it = 0; it < 4; ++it) {
      int ch = tid + it * 256;
      int dim = ch >> 4, pc = ch & 15, lc = pc ^ (dim & 7);
      async_ld16(Vt + ((size_t)hb) * HD + (size_t)dim * L + kvbase + kt * 128 + lc * 8,
                 &Vs[0][0] + ch * 8);
    }
    __syncthreads();                  // staging visible

    // S = Q K^T  (Q pre-scaled by 1/8)
    f32x4 Sv[2][8];
#pragma unroll
    for (int mi = 0; mi < 2; mi++)
#pragma unroll
      for (int nj = 0; nj < 8; nj++) Sv[mi][nj] = (f32x4){0.f, 0.f, 0.f, 0.f};
#pragma unroll
    for (int kq = 0; kq < 2; kq++) {
      int pch = (kq * 4 + q) ^ cx;
      bf16x8 bk[8];
#pragma unroll
      for (int nj = 0; nj < 8; nj++) bk[nj] = *(const bf16x8*)&Ks[nj * 16 + c][pch * 8];
#pragma unroll
      for (int mi = 0; mi < 2; mi++)
#pragma unroll
        for (int nj = 0; nj < 8; nj++)
          Sv[mi][nj] = __builtin_amdgcn_mfma_f32_16x16x32_bf16(aq[mi][kq], bk[nj], Sv[mi][nj], 0, 0, 0);
    }

    // two KV halves of 64: exp+pack 4 vals -> ds_write_b64 into Ps[128][64]; then PV
#pragma unroll
    for (int half = 0; half < 2; ++half) {
#pragma unroll
      for (int mi = 0; mi < 2; mi++)
#pragma unroll
        for (int rg = 0; rg < 4; rg++) {
          bf16x4 p4;
          float rs = 0.f;
#pragma unroll
          for (int j = 0; j < 4; j++) {
            float p = __expf(Sv[mi][half * 4 + j][rg]);
            rs += p;
            p4[j] = (bf16_t)p;
          }
          lrow[mi][rg] += rs;
          int row = wm + mi * 16 + q * 4 + rg;
          int u8 = c ^ ((row & 7) << 1);          // 8B-unit swizzle
          *(bf16x4*)((char*)&Ps[row][0] + u8 * 8) = p4;
        }
      // no barrier: Ps rows wm..wm+31 wave-private (DS ops in-order within a wave)
#pragma unroll
      for (int kk2 = 0; kk2 < 2; ++kk2) {
        bf16x8 ap[2], bv[4];
#pragma unroll
        for (int mi = 0; mi < 2; mi++) {
          int u8 = (kk2 * 8 + q * 2) ^ (cx << 1); // even: b128-aligned
          ap[mi] = *(const bf16x8*)((char*)&Ps[wm + mi * 16 + c][0] + u8 * 8);
        }
#pragma unroll
        for (int vd = 0; vd < 4; vd++) {
          int pch = (half * 8 + kk2 * 4 + q) ^ cx;
          bv[vd] = *(const bf16x8*)&Vs[vd * 16 + c][pch * 8];
        }
#pragma unroll
        for (int mi = 0; mi < 2; mi++)
#pragma unroll
          for (int vd = 0; vd < 4; vd++)
            O[mi][vd] = __builtin_amdgcn_mfma_f32_16x16x32_bf16(ap[mi], bv[vd], O[mi][vd], 0, 0, 0);
      }
    }
  }

  // epilogue: l = cross-lane rowsum; out = O / l / 3, scattered to original positions
  const float inv3 = 1.0f / 3.0f;
#pragma unroll
  for (int mi = 0; mi < 2; mi++)
#pragma unroll
    for (int rg = 0; rg < 4; rg++) {
      float l = lrow[mi][rg];
#pragma unroll
      for (int d = 1; d < 16; d <<= 1) l += __shfl_xor(l, d, 64);
      float invl = inv3 / l;
      int jj = jj0 + wm + mi * 16 + q * 4 + rg;
      int p = si * s + g + ((jj & 2047) << g);
      size_t base = ((size_t)(b * SEQ + p)) * EMB + h * HD;
#pragma unroll
      for (int vd = 0; vd < 4; vd++)
        xattn[base + vd * 16 + c] = (bf16_t)(O[mi][vd][rg] * invl);
    }
}

// ---------- LayerNorm (wave per row, 24B contiguous per lane) ----------
__global__ __launch_bounds__(256)
void k_ln(const bf16_t* __restrict__ x, const float* __restrict__ lnw,
          const float* __restrict__ lnb, bf16_t* __restrict__ y) {
  int wave = threadIdx.x >> 6, lane = threadIdx.x & 63;
  int row = blockIdx.x * 4 + wave;
  const bf16_t* xr = x + (size_t)row * EMB + lane * 12;
  bf16x4 v4[3];
#pragma unroll
  for (int j = 0; j < 3; j++) v4[j] = *(const bf16x4*)(xr + j * 4);
  float v[12], s = 0.f, s2 = 0.f;
#pragma unroll
  for (int j = 0; j < 12; j++) {
    v[j] = (float)v4[j >> 2][j & 3];
    s += v[j];
    s2 += v[j] * v[j];
  }
#pragma unroll
  for (int d = 1; d < 64; d <<= 1) { s += __shfl_xor(s, d, 64); s2 += __shfl_xor(s2, d, 64); }
  float mu = s * (1.f / 768.f);
  float var = s2 * (1.f / 768.f) - mu * mu;
  float rstd = rsqrtf(var + 1e-5f);
  const float4* wr = (const float4*)(lnw + lane * 12);
  const float4* br = (const float4*)(lnb + lane * 12);
  bf16_t* yr = y + (size_t)row * EMB + lane * 12;
#pragma unroll
  for (int j = 0; j < 3; j++) {
    float4 w = wr[j], bb = br[j];
    bf16x4 o;
    o[0] = (bf16_t)((v[j * 4 + 0] - mu) * rstd * w.x + bb.x);
    o[1] = (bf16_t)((v[j * 4 + 1] - mu) * rstd * w.y + bb.y);
    o[2] = (bf16_t)((v[j * 4 + 2] - mu) * rstd * w.z + bb.z);
    o[3] = (bf16_t)((v[j * 4 + 3] - mu) * rstd * w.w + bb.w);
    *(bf16x4*)(yr + j * 4) = o;
  }
}

extern "C" void kernel_launch(void* const* d_in, const int* in_sizes, int n_in,
                              void* d_out, int out_size, void* d_ws, size_t ws_size,
                              hipStream_t stream) {
  const float* query = (const float*)d_in[0];
  const float* key   = (const float*)d_in[1];
  const float* value = (const float*)d_in[2];
  const float* qkv_w = (const float*)d_in[3];
  const float* qkv_b = (const float*)d_in[4];
  const float* ln_w  = (const float*)d_in[5];
  const float* ln_b  = (const float*)d_in[6];
  const float* out_w = (const float*)d_in[7];
  const float* out_b = (const float*)d_in[8];
  float* out = (float*)d_out;

  char* ws = (char*)d_ws;
  const size_t A = (size_t)TOK * EMB * 2;   // 25,165,824 bytes per full-tensor slot
  bf16_t* qb    = (bf16_t*)(ws + 0 * A);    // bf16 query  (later: xattn)
  bf16_t* kb    = (bf16_t*)(ws + 1 * A);    // bf16 key    (later: xnorm)
  bf16_t* vb    = (bf16_t*)(ws + 2 * A);    // bf16 value  (later: Vt, 14.7MB)
  bf16_t* Vb    = (bf16_t*)(ws + 3 * A);    // V projected, [tok][768]
  bf16_t* Qg    = (bf16_t*)(ws + 4 * A);    // gathered Q (pre-scaled 1/8), 14.7MB
  bf16_t* Kg    = (bf16_t*)(ws + 5 * A);    // gathered K, 14.7MB
  bf16_t* wqkv  = (bf16_t*)(ws + 6 * A);
  bf16_t* wout  = (bf16_t*)(ws + 6 * A + (size_t)2304 * 768 * 2);
  // aliases (stream-ordered, lifetimes disjoint):
  bf16_t* Vt    = vb;   // vb dead after qkv GEMM
  bf16_t* xattn = qb;   // qb dead after qkv GEMM
  bf16_t* xnorm = kb;   // kb dead after qkv GEMM

  // 1. casts fp32 -> bf16 (inputs + weights)
  k_cast<<<6144, 256, 0, stream>>>(query, qb, TOK * EMB);
  k_cast<<<6144, 256, 0, stream>>>(key,   kb, TOK * EMB);
  k_cast<<<6144, 256, 0, stream>>>(value, vb, TOK * EMB);
  k_cast<<<864, 256, 0, stream>>>(qkv_w, wqkv, 2304 * 768);
  k_cast<<<288, 256, 0, stream>>>(out_w, wout, 768 * 768);

  // 2. QKV projection (async bf16 staging) + fused Q/K dilated-gather epilogue
  dim3 gq(6, 128, 3);
  k_gemm_qkv<<<gq, 256, 0, stream>>>(qb, kb, vb, wqkv, qkv_b, Qg, Kg, Vb);

  // 3. V gather (transpose + slot-permute)
  dim3 gg(128, 12, 2);
  k_gather_v<<<gg, 256, 0, stream>>>(Vb, Vt);

  // 4. attention (zero xattn first: non-selected positions must be 0)
  hipMemsetAsync(xattn, 0, A, stream);
  k_attn<<<896, 256, 0, stream>>>(Qg, Kg, Vt, xattn);

  // 5. MAGNETO LN
  k_ln<<<4096, 256, 0, stream>>>(xattn, ln_w, ln_b, xnorm);

  // 6. output projection
  dim3 go(6, 128);
  k_gemm_out<<<go, 256, 0, stream>>>(xnorm, wout, out_b, out);
}